// Round 8
// baseline (2413.275 us; speedup 1.0000x reference)
//
#include <hip/hip_runtime.h>
#include <stdint.h>

typedef unsigned short u16;
typedef __attribute__((ext_vector_type(4))) float f32x4;
typedef __attribute__((ext_vector_type(8))) __bf16 bf16x8;

typedef __attribute__((address_space(1))) void as1_void;
typedef __attribute__((address_space(3))) void as3_void;

#define SCALE_Q 11.313708498984761f

static_assert(sizeof(bf16x8) == 16, "bf16x8 must be 16B");

__device__ __forceinline__ u16 f2bf(float x) {
  union { float f; unsigned u; } v; v.f = x;
  return (u16)((v.u + 0x7FFFu + ((v.u >> 16) & 1u)) >> 16);
}
__device__ __forceinline__ float bf2f(u16 h) {
  union { unsigned u; float f; } v; v.u = ((unsigned)h) << 16;
  return v.f;
}
__device__ __forceinline__ f32x4 mfma16(bf16x8 a, bf16x8 b, f32x4 c) {
  return __builtin_amdgcn_mfma_f32_16x16x32_bf16(a, b, c, 0, 0, 0);
}
__device__ __forceinline__ void gload_lds16(const void* g, void* lds) {
  __builtin_amdgcn_global_load_lds((as1_void*)g, (as3_void*)lds, 16, 0, 0);
}

// ---------------- convert: fp32 -> bf16 hi/lo ----------------
__global__ void k_convert(const float* __restrict__ X, u16* __restrict__ Xh,
                          u16* __restrict__ Xl) {
  long idx = ((long)blockIdx.x * 256 + threadIdx.x) * 8;
  float4 a = *(const float4*)(X + idx);
  float4 b = *(const float4*)(X + idx + 4);
  float xs[8] = {a.x, a.y, a.z, a.w, b.x, b.y, b.z, b.w};
  union { u16 s[8]; uint4 v; } hu, lu;
#pragma unroll
  for (int i = 0; i < 8; ++i) {
    u16 h = f2bf(xs[i]);
    hu.s[i] = h;
    lu.s[i] = f2bf(xs[i] - bf2f(h));
  }
  *(uint4*)(Xh + idx) = hu.v;
  *(uint4*)(Xl + idx) = lu.v;
}

// ================ QKV GEMM v3: 128x128 tile, 4 waves, BK=32 packed rows,
// single-buffered, 32 KiB LDS -> 4 blocks/CU (cross-block overlap = m97 mechanism) ====
// C[m,f] = sum_e X[m,e] * W[f,e].  m = s*2+b.  f = h*768 + {q,k,v} * 256
// LDS row = 64 elems = 128B = 8 chunks of 8: qk: chunks 0-3 hi(k0..k0+31), 4-7 lo;
// v: chunks 0-7 hi (BK=64). Stored swizzled: LDS[row][slot] = logical[slot ^ (row&7)]
__launch_bounds__(256, 4)
__global__ void k_qkv3(const u16* __restrict__ Xh, const u16* __restrict__ Xl,
                       const u16* __restrict__ Wh, const u16* __restrict__ Wl,
                       u16* __restrict__ Qh, u16* __restrict__ Ql,
                       u16* __restrict__ Kh, u16* __restrict__ Kl,
                       u16* __restrict__ Vv) {
  const int bid = blockIdx.x;
  const int swz = (bid & 7) * 384 + (bid >> 3);  // 3072 % 8 == 0 -> bijective
  const int nt = swz % 96, mt = swz / 96;
  const int n0 = nt * 128, m0 = mt * 128;
  const int seg = (n0 % 768) / 256;  // 0=q 1=k 2=v (128-tiles never straddle)
  const bool qk = (seg < 2);
  const int hblk = n0 / 768;
  const int rbase = (n0 % 768) - seg * 256;  // 0 or 128 within segment

  __shared__ u16 S[2][128 * 64];  // [A/B][tile] = 32 KiB total

  const int tid = threadIdx.x;
  const int lane = tid & 63, w = tid >> 6;  // 4 waves
  const int wr = w >> 1, wc = w & 1;        // 2x2 wave grid; wave tile 64x64
  const int l15 = lane & 15, l4 = lane >> 4;

  const bool stB = (w >= 2);
  const int r_in = lane >> 3;   // row within 1KB inst
  const int c_in = lane & 7;    // dest slot
  const u16* g_hi = stB ? Wh : Xh;
  const u16* g_lo = stB ? Wl : Xl;
  const int gr0 = (stB ? n0 : m0);

  const int sh = (l4 ^ (l15 & 7)) * 8;        // hi chunk slot (qk)
  const int sl = ((l4 ^ 4) ^ (l15 & 7)) * 8;  // lo chunk slot (qk)

  const f32x4 zero4 = {0.f, 0.f, 0.f, 0.f};
  f32x4 acc[4][4];
#pragma unroll
  for (int i = 0; i < 4; i++)
#pragma unroll
    for (int j = 0; j < 4; j++) acc[i][j] = zero4;

  if (qk) {
    for (int t = 0; t < 128; ++t) {
      const int k0 = t * 32;
      // stage (A: waves 0-1, B: waves 2-3; 8 insts each; hi/lo via chunk swizzle)
#pragma unroll
      for (int q8 = 0; q8 < 8; ++q8) {
        const int qi = (w & 1) * 8 + q8;  // inst 0..15 within tile
        const int row = qi * 8 + r_in;
        const int cs = c_in ^ (row & 7);
        const u16* src = (cs < 4) ? g_hi : g_lo;
        const int col = k0 + (cs & 3) * 8;
        gload_lds16(src + (size_t)(gr0 + row) * 4096 + col, &S[stB ? 1 : 0][qi * 512]);
      }
      __syncthreads();  // loads landed (vmcnt drain; other blocks cover the stall)
      bf16x8 ah[4], al[4];
#pragma unroll
      for (int i = 0; i < 4; i++) {
        const int rb = (wr * 64 + i * 16 + l15) * 64;
        ah[i] = *(const bf16x8*)&S[0][rb + sh];
        al[i] = *(const bf16x8*)&S[0][rb + sl];
      }
      __builtin_amdgcn_s_setprio(1);
#pragma unroll
      for (int j = 0; j < 4; j++) {
        const int rb = (wc * 64 + j * 16 + l15) * 64;
        bf16x8 bh = *(const bf16x8*)&S[1][rb + sh];
        bf16x8 bl = *(const bf16x8*)&S[1][rb + sl];
#pragma unroll
        for (int i = 0; i < 4; i++) {
          acc[i][j] = mfma16(ah[i], bh, acc[i][j]);
          acc[i][j] = mfma16(ah[i], bl, acc[i][j]);
          acc[i][j] = mfma16(al[i], bh, acc[i][j]);
        }
      }
      __builtin_amdgcn_s_setprio(0);
      __syncthreads();  // all waves done reading; next iter overwrites
    }
  } else {
    for (int t = 0; t < 64; ++t) {
      const int k0 = t * 64;
#pragma unroll
      for (int q8 = 0; q8 < 8; ++q8) {
        const int qi = (w & 1) * 8 + q8;
        const int row = qi * 8 + r_in;
        const int cs = c_in ^ (row & 7);
        gload_lds16(g_hi + (size_t)(gr0 + row) * 4096 + k0 + cs * 8, &S[stB ? 1 : 0][qi * 512]);
      }
      __syncthreads();
      __builtin_amdgcn_s_setprio(1);
#pragma unroll
      for (int kc = 0; kc < 2; kc++) {
        const int so = ((kc * 4 + l4) ^ (l15 & 7)) * 8;
        bf16x8 av[4];
#pragma unroll
        for (int i = 0; i < 4; i++)
          av[i] = *(const bf16x8*)&S[0][(wr * 64 + i * 16 + l15) * 64 + so];
#pragma unroll
        for (int j = 0; j < 4; j++) {
          bf16x8 bv = *(const bf16x8*)&S[1][(wc * 64 + j * 16 + l15) * 64 + so];
#pragma unroll
          for (int i = 0; i < 4; i++) acc[i][j] = mfma16(av[i], bv, acc[i][j]);
        }
      }
      __builtin_amdgcn_s_setprio(0);
      __syncthreads();
    }
  }

  // epilogue: scatter into per-(b,h) layouts; fold sqrt(128) into Q
#pragma unroll
  for (int i = 0; i < 4; i++)
#pragma unroll
    for (int j = 0; j < 4; j++)
#pragma unroll
      for (int jj = 0; jj < 4; jj++) {
        const int mrow = m0 + wr * 64 + i * 16 + l4 * 4 + jj;
        const int ecol = rbase + wc * 64 + j * 16 + l15;
        const int srow = mrow >> 1, b = mrow & 1;
        const size_t o = ((size_t)(b * 16 + hblk) * 2048 + srow) * 256 + ecol;
        float v = acc[i][j][jj];
        if (seg == 0) {
          v *= SCALE_Q;
          u16 hb = f2bf(v);
          Qh[o] = hb;
          Ql[o] = f2bf(v - bf2f(hb));
        } else if (seg == 1) {
          u16 hb = f2bf(v);
          Kh[o] = hb;
          Kl[o] = f2bf(v - bf2f(hb));
        } else {
          Vv[o] = f2bf(v);
        }
      }
}

// ---------------- V [bh][s][e] -> Vt [bh][e][s] ----------------
__global__ void k_transpose(const u16* __restrict__ Vv, u16* __restrict__ Vt) {
  const int bidx = blockIdx.x;
  const int et = bidx & 3;
  const int st = (bidx >> 2) & 31;
  const int bh = bidx >> 7;
  const int s0 = st * 64, e0 = et * 64;
  __shared__ u16 T[64][72];
  const int t = threadIdx.x;
  const int r = t >> 2, c = t & 3;
  const u16* src = Vv + (size_t)bh * 524288 + (size_t)(s0 + r) * 256 + e0 + c * 16;
  uint4 a = *(const uint4*)src;
  uint4 b = *(const uint4*)(src + 8);
  *(uint4*)&T[r][c * 16] = a;
  *(uint4*)&T[r][c * 16 + 8] = b;
  __syncthreads();
  union { u16 s[16]; uint4 v[2]; } pk;
#pragma unroll
  for (int i = 0; i < 16; i++) pk.s[i] = T[c * 16 + i][r];
  u16* dst = Vt + (size_t)bh * 524288 + (size_t)(e0 + r) * 2048 + s0 + c * 16;
  *(uint4*)dst = pk.v[0];
  *(uint4*)(dst + 8) = pk.v[1];
}

// ---------------- flash attention (round-3 proven form, verbatim) ----------------
__launch_bounds__(256, 2)
__global__ void k_attn(const u16* __restrict__ Qh, const u16* __restrict__ Ql,
                       const u16* __restrict__ Kh, const u16* __restrict__ Kl,
                       const u16* __restrict__ Vt, u16* __restrict__ Y) {
  const int pairIdx = blockIdx.x & 15;
  const int bh = blockIdx.x >> 4;
  const int b = bh >> 4, h = bh & 15;
  const int tid = threadIdx.x, lane = tid & 63, w = tid >> 6;
  const int l15 = lane & 15, l4 = lane >> 4;

  __shared__ u16 sKh[32 * 264];
  __shared__ u16 sKl[32 * 264];
  __shared__ u16 sVt[256 * 40];
  __shared__ u16 sP[64 * 40];
  __shared__ float sR[64];
  __shared__ float sL[64];

  const u16* Qhb = Qh + (size_t)bh * 524288;
  const u16* Qlb = Ql + (size_t)bh * 524288;
  const u16* Khb = Kh + (size_t)bh * 524288;
  const u16* Klb = Kl + (size_t)bh * 524288;
  const u16* Vtb = Vt + (size_t)bh * 524288;

  const int qb = (w >> 1) * 32;
  const int eb = (w & 1) * 128;
  const f32x4 zero4 = {0.f, 0.f, 0.f, 0.f};

  for (int rep = 0; rep < 2; ++rep) {
    const int tile = rep ? (31 - pairIdx) : pairIdx;
    const int q0 = tile * 64;
    bf16x8 qfh[8], qfl[8];
    {
      const int qrow = q0 + 16 * w + l15;
      const u16* ph = Qhb + (size_t)qrow * 256 + l4 * 8;
      const u16* pl = Qlb + (size_t)qrow * 256 + l4 * 8;
#pragma unroll
      for (int kc = 0; kc < 8; kc++) {
        qfh[kc] = *(const bf16x8*)(ph + kc * 32);
        qfl[kc] = *(const bf16x8*)(pl + kc * 32);
      }
    }
    f32x4 acc[2][8];
#pragma unroll
    for (int qf = 0; qf < 2; qf++)
#pragma unroll
      for (int ef = 0; ef < 8; ef++) acc[qf][ef] = zero4;
    float m_run[4], l_run[4];
#pragma unroll
    for (int jj = 0; jj < 4; jj++) { m_run[jj] = -1e30f; l_run[jj] = 0.f; }

    const int nsteps = 2 * tile + 2;
    for (int st2 = 0; st2 < nsteps; ++st2) {
      const int k0 = st2 * 32;
#pragma unroll
      for (int i = 0; i < 4; i++) {
        const int sl2 = tid + 256 * i;
        const int key = sl2 >> 5, c = sl2 & 31;
        const size_t go = (size_t)(k0 + key) * 256 + c * 8;
        uint4 vh = *(const uint4*)(Khb + go);
        uint4 vl = *(const uint4*)(Klb + go);
        *(uint4*)&sKh[key * 264 + c * 8] = vh;
        *(uint4*)&sKl[key * 264 + c * 8] = vl;
      }
#pragma unroll
      for (int i = 0; i < 4; i++) {
        const int sl2 = tid + 256 * i;
        const int e = sl2 >> 2, c = sl2 & 3;
        uint4 vv = *(const uint4*)(Vtb + (size_t)e * 2048 + k0 + c * 8);
        *(uint4*)&sVt[e * 40 + c * 8] = vv;
      }
      __syncthreads();
      f32x4 shh[2], shl[2], slh[2];
#pragma unroll
      for (int cf = 0; cf < 2; cf++) { shh[cf] = zero4; shl[cf] = zero4; slh[cf] = zero4; }
#pragma unroll
      for (int kc = 0; kc < 8; kc++) {
#pragma unroll
        for (int cf = 0; cf < 2; cf++) {
          const int eo = (cf * 16 + l15) * 264 + kc * 32 + l4 * 8;
          bf16x8 kbh = *(const bf16x8*)&sKh[eo];
          bf16x8 kbl = *(const bf16x8*)&sKl[eo];
          shh[cf] = mfma16(qfh[kc], kbh, shh[cf]);
          shl[cf] = mfma16(qfh[kc], kbl, shl[cf]);
          slh[cf] = mfma16(qfl[kc], kbh, slh[cf]);
        }
      }
#pragma unroll
      for (int jj = 0; jj < 4; jj++) {
        const int prow = 16 * w + l4 * 4 + jj;
        const int qrow = q0 + prow;
        float s0v = shh[0][jj] + shl[0][jj] + slh[0][jj];
        float s1v = shh[1][jj] + shl[1][jj] + slh[1][jj];
        if (k0 + l15 > qrow) s0v = -1e30f;
        if (k0 + 16 + l15 > qrow) s1v = -1e30f;
        float mx = fmaxf(s0v, s1v);
#pragma unroll
        for (int off = 1; off < 16; off <<= 1) mx = fmaxf(mx, __shfl_xor(mx, off, 64));
        const float mnew = fmaxf(m_run[jj], mx);
        const float r = __expf(m_run[jj] - mnew);
        const float p0 = __expf(s0v - mnew);
        const float p1 = __expf(s1v - mnew);
        float rs = p0 + p1;
#pragma unroll
        for (int off = 1; off < 16; off <<= 1) rs += __shfl_xor(rs, off, 64);
        l_run[jj] = l_run[jj] * r + rs;
        m_run[jj] = mnew;
        sP[prow * 40 + l15] = f2bf(p0);
        sP[prow * 40 + 16 + l15] = f2bf(p1);
        if (l15 == 0) { sR[prow] = r; sL[prow] = l_run[jj]; }
      }
      __syncthreads();
      float rr[2][4];
#pragma unroll
      for (int qf = 0; qf < 2; qf++)
#pragma unroll
        for (int jj = 0; jj < 4; jj++) rr[qf][jj] = sR[qb + qf * 16 + l4 * 4 + jj];
#pragma unroll
      for (int qf = 0; qf < 2; qf++)
#pragma unroll
        for (int ef = 0; ef < 8; ef++)
#pragma unroll
          for (int jj = 0; jj < 4; jj++) acc[qf][ef][jj] *= rr[qf][jj];
      bf16x8 pa[2];
#pragma unroll
      for (int qf = 0; qf < 2; qf++)
        pa[qf] = *(const bf16x8*)&sP[(qb + qf * 16 + l15) * 40 + l4 * 8];
#pragma unroll
      for (int ef = 0; ef < 8; ef++) {
        bf16x8 vb = *(const bf16x8*)&sVt[(eb + ef * 16 + l15) * 40 + l4 * 8];
#pragma unroll
        for (int qf = 0; qf < 2; qf++) acc[qf][ef] = mfma16(pa[qf], vb, acc[qf][ef]);
      }
      __syncthreads();
    }
    float li[2][4];
#pragma unroll
    for (int qf = 0; qf < 2; qf++)
#pragma unroll
      for (int jj = 0; jj < 4; jj++) li[qf][jj] = 1.0f / sL[qb + qf * 16 + l4 * 4 + jj];
#pragma unroll
    for (int qf = 0; qf < 2; qf++)
#pragma unroll
      for (int ef = 0; ef < 8; ef++)
#pragma unroll
        for (int jj = 0; jj < 4; jj++) {
          const int qrow = q0 + qb + qf * 16 + l4 * 4 + jj;
          const int mrow = qrow * 2 + b;
          const int col = h * 256 + eb + ef * 16 + l15;
          Y[(size_t)mrow * 4096 + col] = f2bf(acc[qf][ef][jj] * li[qf][jj]);
        }
    __syncthreads();
  }
}

// ---------------- proj GEMM (round-2/3 proven form) ----------------
__launch_bounds__(256, 2)
__global__ void k_proj(const u16* __restrict__ Yb, const u16* __restrict__ Wph,
                       float* __restrict__ Out) {
  const int n0 = blockIdx.x * 128;
  const int m0 = blockIdx.y * 128;
  __shared__ u16 sA[128 * 64];
  __shared__ u16 sB[128 * 64];
  const int tid = threadIdx.x;
  const int lane = tid & 63, w = tid >> 6;
  const int wr = w >> 1, wc = w & 1;
  const int l15 = lane & 15, l4 = lane >> 4;
  const f32x4 zero4 = {0.f, 0.f, 0.f, 0.f};
  f32x4 acc[4][4];
#pragma unroll
  for (int i = 0; i < 4; i++)
#pragma unroll
    for (int j = 0; j < 4; j++) acc[i][j] = zero4;

  for (int k0 = 0; k0 < 4096; k0 += 64) {
#pragma unroll
    for (int ii = 0; ii < 4; ++ii) {
      const int inst = w * 4 + ii;
      const int o = inst * 1024 + lane * 16;
      const int mr = o >> 7, c = (o & 127) >> 4;
      const int cs = c ^ (mr & 7);
      gload_lds16(Yb + (size_t)(m0 + mr) * 4096 + k0 + cs * 8, (char*)sA + inst * 1024);
      gload_lds16(Wph + (size_t)(n0 + mr) * 4096 + k0 + cs * 8, (char*)sB + inst * 1024);
    }
    __syncthreads();
#pragma unroll
    for (int kc = 0; kc < 2; ++kc) {
      bf16x8 af[4], bff[4];
#pragma unroll
      for (int i = 0; i < 4; i++) {
        const int mr = wr * 64 + i * 16 + l15;
        const int ch = (kc * 4 + l4) ^ (mr & 7);
        af[i] = *(const bf16x8*)&sA[mr * 64 + ch * 8];
      }
#pragma unroll
      for (int j = 0; j < 4; j++) {
        const int nr = wc * 64 + j * 16 + l15;
        const int ch = (kc * 4 + l4) ^ (nr & 7);
        bff[j] = *(const bf16x8*)&sB[nr * 64 + ch * 8];
      }
#pragma unroll
      for (int i = 0; i < 4; i++)
#pragma unroll
        for (int j = 0; j < 4; j++) acc[i][j] = mfma16(af[i], bff[j], acc[i][j]);
    }
    __syncthreads();
  }
#pragma unroll
  for (int i = 0; i < 4; i++)
#pragma unroll
    for (int j = 0; j < 4; j++)
#pragma unroll
      for (int jj = 0; jj < 4; jj++) {
        const int mrow = m0 + wr * 64 + i * 16 + l4 * 4 + jj;
        const int ncol = n0 + wc * 64 + j * 16 + l15;
        Out[(size_t)mrow * 2048 + ncol] = acc[i][j][jj];
      }
}

// ---------------- launcher ----------------
extern "C" void kernel_launch(void* const* d_in, const int* in_sizes, int n_in,
                              void* d_out, int out_size, void* d_ws, size_t ws_size,
                              hipStream_t stream) {
  (void)in_sizes; (void)n_in; (void)out_size; (void)ws_size;
  const float* X = (const float*)d_in[0];
  const float* Wq = (const float*)d_in[2];
  const float* Wp = (const float*)d_in[3];
  float* Out = (float*)d_out;
  char* ws = (char*)d_ws;
  const size_t MB = 1ull << 20;
  u16* Xh = (u16*)(ws + 0 * 32 * MB);
  u16* Xl = (u16*)(ws + 1 * 32 * MB);
  u16* Qh = (u16*)(ws + 2 * 32 * MB);
  u16* Ql = (u16*)(ws + 3 * 32 * MB);
  u16* Kh = (u16*)(ws + 4 * 32 * MB);
  u16* Kl = (u16*)(ws + 5 * 32 * MB);
  u16* Vv = (u16*)(ws + 6 * 32 * MB);
  u16* Wh = (u16*)(ws + 224 * MB);  // 96 MB
  u16* Wl = (u16*)(ws + 320 * MB);  // 96 MB
  u16* Vt = Wh;                     // alias: Wh dead after k_qkv3
  u16* Y = Wl;                      // alias: Wl dead after k_qkv3
  u16* Wph = Kh;                    // alias: Kh dead after k_attn
  u16* Wpl = Kl;                    // alias: Kl dead after k_attn

  k_convert<<<8192, 256, 0, stream>>>(X, Xh, Xl);
  k_convert<<<24576, 256, 0, stream>>>(Wq, Wh, Wl);
  k_qkv3<<<3072, 256, 0, stream>>>(Xh, Xl, Wh, Wl, Qh, Ql, Kh, Kl, Vv);
  k_transpose<<<4096, 256, 0, stream>>>(Vv, Vt);
  k_attn<<<512, 256, 0, stream>>>(Qh, Ql, Kh, Kl, Vt, Y);
  k_convert<<<4096, 256, 0, stream>>>(Wp, Wph, Wpl);
  k_proj<<<dim3(16, 32), 256, 0, stream>>>(Y, Wph, Out);
}

// Round 9
// 1509.820 us; speedup vs baseline: 1.5984x; 1.5984x over previous
//
#include <hip/hip_runtime.h>
#include <stdint.h>

typedef unsigned short u16;
typedef __attribute__((ext_vector_type(4))) float f32x4;
typedef __attribute__((ext_vector_type(8))) __bf16 bf16x8;

typedef __attribute__((address_space(1))) void as1_void;
typedef __attribute__((address_space(3))) void as3_void;

#define SCALE_Q 11.313708498984761f

static_assert(sizeof(bf16x8) == 16, "bf16x8 must be 16B");

__device__ __forceinline__ u16 f2bf(float x) {
  union { float f; unsigned u; } v; v.f = x;
  return (u16)((v.u + 0x7FFFu + ((v.u >> 16) & 1u)) >> 16);
}
__device__ __forceinline__ float bf2f(u16 h) {
  union { unsigned u; float f; } v; v.u = ((unsigned)h) << 16;
  return v.f;
}
__device__ __forceinline__ f32x4 mfma16(bf16x8 a, bf16x8 b, f32x4 c) {
  return __builtin_amdgcn_mfma_f32_16x16x32_bf16(a, b, c, 0, 0, 0);
}
__device__ __forceinline__ void gload_lds16(const void* g, void* lds) {
  __builtin_amdgcn_global_load_lds((as1_void*)g, (as3_void*)lds, 16, 0, 0);
}

// ---------------- convert: fp32 -> bf16 hi/lo ----------------
__global__ void k_convert(const float* __restrict__ X, u16* __restrict__ Xh,
                          u16* __restrict__ Xl) {
  long idx = ((long)blockIdx.x * 256 + threadIdx.x) * 8;
  float4 a = *(const float4*)(X + idx);
  float4 b = *(const float4*)(X + idx + 4);
  float xs[8] = {a.x, a.y, a.z, a.w, b.x, b.y, b.z, b.w};
  union { u16 s[8]; uint4 v; } hu, lu;
#pragma unroll
  for (int i = 0; i < 8; ++i) {
    u16 h = f2bf(xs[i]);
    hu.s[i] = h;
    lu.s[i] = f2bf(xs[i] - bf2f(h));
  }
  *(uint4*)(Xh + idx) = hu.v;
  *(uint4*)(Xl + idx) = lu.v;
}

// ================ QKV GEMM (round-3 proven form, supply-roofline): 256x256, 8 waves ====
__launch_bounds__(512, 2)
__global__ void k_qkv2(const u16* __restrict__ Xh, const u16* __restrict__ Xl,
                       const u16* __restrict__ Wh, const u16* __restrict__ Wl,
                       u16* __restrict__ Qh, u16* __restrict__ Ql,
                       u16* __restrict__ Kh, u16* __restrict__ Kl,
                       u16* __restrict__ Vv) {
  const int bid = blockIdx.x;
  const int swz = (bid & 7) * 96 + (bid >> 3);  // 768 % 8 == 0 -> bijective
  const int nt = swz % 48, mt = swz / 48;
  const int n0 = nt * 256, m0 = mt * 256;
  const int seg = (n0 % 768) / 256;  // 0=q 1=k 2=v
  const bool qk = (seg < 2);
  const int hblk = n0 / 768;

  __shared__ u16 S[2][2][256 * 64];  // [buf][A/B][tile] = 128 KiB

  const int tid = threadIdx.x;
  const int lane = tid & 63, w = tid >> 6;
  const int wm = w >> 2, wn = w & 3;
  const int l15 = lane & 15, l4 = lane >> 4;

  const bool stB = (w >= 4);
  const int r_in = lane >> 3;
  const int c_in = lane & 7;
  const u16* g_hi = stB ? Wh : Xh;
  const u16* g_lo = stB ? Wl : Xl;
  const int gr0 = (stB ? n0 : m0);

  const int sh = (l4 ^ (l15 & 7)) * 8;
  const int sl = ((l4 ^ 4) ^ (l15 & 7)) * 8;

  const f32x4 zero4 = {0.f, 0.f, 0.f, 0.f};
  f32x4 acc[8][4];
#pragma unroll
  for (int i = 0; i < 8; i++)
#pragma unroll
    for (int j = 0; j < 4; j++) acc[i][j] = zero4;

  if (qk) {
    auto stage = [&](int buf, int k0) {
#pragma unroll
      for (int q8 = 0; q8 < 8; ++q8) {
        const int qi = (w & 3) * 8 + q8;
        const int row = qi * 8 + r_in;
        const int cs = c_in ^ (row & 7);
        const u16* src = (cs < 4) ? g_hi : g_lo;
        const int col = k0 + (cs & 3) * 8;
        gload_lds16(src + (size_t)(gr0 + row) * 4096 + col, &S[buf][stB ? 1 : 0][qi * 512]);
      }
    };
    stage(0, 0);
    __syncthreads();
    for (int t = 0; t < 128; ++t) {
      const int cur = t & 1;
      if (t + 1 < 128) stage(cur ^ 1, (t + 1) * 32);
      const u16* sAc = &S[cur][0][0];
      const u16* sBc = &S[cur][1][0];
      bf16x8 ah[8], al[8];
#pragma unroll
      for (int i = 0; i < 8; i++) {
        const int rb = (wm * 128 + i * 16 + l15) * 64;
        ah[i] = *(const bf16x8*)&sAc[rb + sh];
        al[i] = *(const bf16x8*)&sAc[rb + sl];
      }
      __builtin_amdgcn_s_setprio(1);
#pragma unroll
      for (int j = 0; j < 4; j++) {
        const int rb = (wn * 64 + j * 16 + l15) * 64;
        bf16x8 bh = *(const bf16x8*)&sBc[rb + sh];
        bf16x8 bl = *(const bf16x8*)&sBc[rb + sl];
#pragma unroll
        for (int i = 0; i < 8; i++) {
          acc[i][j] = mfma16(ah[i], bh, acc[i][j]);
          acc[i][j] = mfma16(ah[i], bl, acc[i][j]);
          acc[i][j] = mfma16(al[i], bh, acc[i][j]);
        }
      }
      __builtin_amdgcn_s_setprio(0);
      __syncthreads();
    }
  } else {
    auto stage = [&](int buf, int k0) {
#pragma unroll
      for (int q8 = 0; q8 < 8; ++q8) {
        const int qi = (w & 3) * 8 + q8;
        const int row = qi * 8 + r_in;
        const int cs = c_in ^ (row & 7);
        gload_lds16(g_hi + (size_t)(gr0 + row) * 4096 + k0 + cs * 8, &S[buf][stB ? 1 : 0][qi * 512]);
      }
    };
    stage(0, 0);
    __syncthreads();
    for (int t = 0; t < 64; ++t) {
      const int cur = t & 1;
      if (t + 1 < 64) stage(cur ^ 1, (t + 1) * 64);
      const u16* sAc = &S[cur][0][0];
      const u16* sBc = &S[cur][1][0];
      __builtin_amdgcn_s_setprio(1);
#pragma unroll
      for (int kc = 0; kc < 2; kc++) {
        const int so = ((kc * 4 + l4) ^ (l15 & 7)) * 8;
        bf16x8 av[8];
#pragma unroll
        for (int i = 0; i < 8; i++)
          av[i] = *(const bf16x8*)&sAc[(wm * 128 + i * 16 + l15) * 64 + so];
#pragma unroll
        for (int j = 0; j < 4; j++) {
          bf16x8 bv = *(const bf16x8*)&sBc[(wn * 64 + j * 16 + l15) * 64 + so];
#pragma unroll
          for (int i = 0; i < 8; i++) acc[i][j] = mfma16(av[i], bv, acc[i][j]);
        }
      }
      __builtin_amdgcn_s_setprio(0);
      __syncthreads();
    }
  }

#pragma unroll
  for (int i = 0; i < 8; i++)
#pragma unroll
    for (int j = 0; j < 4; j++)
#pragma unroll
      for (int jj = 0; jj < 4; jj++) {
        const int mrow = m0 + wm * 128 + i * 16 + l4 * 4 + jj;
        const int ecol = wn * 64 + j * 16 + l15;
        const int srow = mrow >> 1, b = mrow & 1;
        const size_t o = ((size_t)(b * 16 + hblk) * 2048 + srow) * 256 + ecol;
        float v = acc[i][j][jj];
        if (seg == 0) {
          v *= SCALE_Q;
          u16 hb = f2bf(v);
          Qh[o] = hb;
          Ql[o] = f2bf(v - bf2f(hb));
        } else if (seg == 1) {
          u16 hb = f2bf(v);
          Kh[o] = hb;
          Kl[o] = f2bf(v - bf2f(hb));
        } else {
          Vv[o] = f2bf(v);
        }
      }
}

// ---------------- V [bh][s][e] -> Vt [bh][e][s] ----------------
__global__ void k_transpose(const u16* __restrict__ Vv, u16* __restrict__ Vt) {
  const int bidx = blockIdx.x;
  const int et = bidx & 3;
  const int st = (bidx >> 2) & 31;
  const int bh = bidx >> 7;
  const int s0 = st * 64, e0 = et * 64;
  __shared__ u16 T[64][72];
  const int t = threadIdx.x;
  const int r = t >> 2, c = t & 3;
  const u16* src = Vv + (size_t)bh * 524288 + (size_t)(s0 + r) * 256 + e0 + c * 16;
  uint4 a = *(const uint4*)src;
  uint4 b = *(const uint4*)(src + 8);
  *(uint4*)&T[r][c * 16] = a;
  *(uint4*)&T[r][c * 16 + 8] = b;
  __syncthreads();
  union { u16 s[16]; uint4 v[2]; } pk;
#pragma unroll
  for (int i = 0; i < 16; i++) pk.s[i] = T[c * 16 + i][r];
  u16* dst = Vt + (size_t)bh * 524288 + (size_t)(e0 + r) * 2048 + s0 + c * 16;
  *(uint4*)dst = pk.v[0];
  *(uint4*)(dst + 8) = pk.v[1];
}

// ---------------- flash attention v2: gload_lds staging, dbuf, wave-owned rows ----------------
// 4 waves; wave w owns q-rows 16w..16w+15 for QK^T AND PV (P/r/l wave-local, 1 barrier/step).
// K LDS rows 256 elems (512B, 32 slots of 8): slot^(row&7) swizzle (qkv2-proven math).
// V LDS rows 32 elems (64B, 4 slots of 8): slot^(row&3) swizzle.
__launch_bounds__(256, 1)
__global__ void k_attn(const u16* __restrict__ Qh, const u16* __restrict__ Ql,
                       const u16* __restrict__ Kh, const u16* __restrict__ Kl,
                       const u16* __restrict__ Vt, u16* __restrict__ Y) {
  const int pairIdx = blockIdx.x & 15;
  const int bh = blockIdx.x >> 4;
  const int b = bh >> 4, h = bh & 15;
  const int tid = threadIdx.x, lane = tid & 63, w = tid >> 6;  // 4 waves
  const int l15 = lane & 15, l4 = lane >> 4;

  __shared__ u16 SKh[2][32 * 256];  // 32 KiB
  __shared__ u16 SKl[2][32 * 256];  // 32 KiB
  __shared__ u16 SV[2][256 * 32];   // 32 KiB
  __shared__ u16 sP[64 * 40];       // wave-local P regions

  const u16* Qhb = Qh + (size_t)bh * 524288;
  const u16* Qlb = Ql + (size_t)bh * 524288;
  const u16* Khb = Kh + (size_t)bh * 524288;
  const u16* Klb = Kl + (size_t)bh * 524288;
  const u16* Vtb = Vt + (size_t)bh * 524288;

  const int kr_in = lane >> 5;   // K: row within 1KB inst (2 rows of 512B)
  const int ks_in = lane & 31;   // K: 16B slot within row
  const int vr_in = lane >> 2;   // V: row within 1KB inst (16 rows of 64B)
  const int vs_in = lane & 3;    // V: 16B slot within row

  const f32x4 zero4 = {0.f, 0.f, 0.f, 0.f};

  for (int rep = 0; rep < 2; ++rep) {
    const int tile = rep ? (31 - pairIdx) : pairIdx;  // paired for load balance
    const int q0 = tile * 64;
    // Q fragments (hi/lo) in registers
    bf16x8 qfh[8], qfl[8];
    {
      const int qrow = q0 + 16 * w + l15;
      const u16* ph = Qhb + (size_t)qrow * 256 + l4 * 8;
      const u16* pl = Qlb + (size_t)qrow * 256 + l4 * 8;
#pragma unroll
      for (int kc = 0; kc < 8; kc++) {
        qfh[kc] = *(const bf16x8*)(ph + kc * 32);
        qfl[kc] = *(const bf16x8*)(pl + kc * 32);
      }
    }
    f32x4 acc[16];
#pragma unroll
    for (int ef = 0; ef < 16; ef++) acc[ef] = zero4;
    float m_run[4], l_run[4];
#pragma unroll
    for (int jj = 0; jj < 4; jj++) { m_run[jj] = -1e30f; l_run[jj] = 0.f; }

    const int nsteps = 2 * tile + 2;  // always even

    auto stage = [&](int buf, int k0) {
#pragma unroll
      for (int q4 = 0; q4 < 4; ++q4) {
        const int qi = w * 4 + q4;  // 0..15
        {  // K hi+lo: inst covers keys qi*2, qi*2+1
          const int row = qi * 2 + kr_in;
          const int cs = ks_in ^ (row & 7);
          const size_t src = (size_t)(k0 + row) * 256 + cs * 8;
          gload_lds16(Khb + src, &SKh[buf][qi * 512]);
          gload_lds16(Klb + src, &SKl[buf][qi * 512]);
        }
        {  // V: inst covers e-rows qi*16..qi*16+15
          const int row = qi * 16 + vr_in;
          const int cs = vs_in ^ (row & 3);
          gload_lds16(Vtb + (size_t)row * 2048 + k0 + cs * 8, &SV[buf][qi * 512]);
        }
      }
    };

    stage(0, 0);
    __syncthreads();

    for (int st2 = 0; st2 < nsteps; ++st2) {
      const int k0 = st2 * 32;
      const int cur = st2 & 1;
      if (st2 + 1 < nsteps) stage(cur ^ 1, k0 + 32);
      // ---- QK^T 3-pass (wave's 16 q-rows x 32 keys) ----
      f32x4 shh[2], shl[2], slh[2];
#pragma unroll
      for (int cf = 0; cf < 2; cf++) { shh[cf] = zero4; shl[cf] = zero4; slh[cf] = zero4; }
      __builtin_amdgcn_s_setprio(1);
#pragma unroll
      for (int kc = 0; kc < 8; kc++) {
#pragma unroll
        for (int cf = 0; cf < 2; cf++) {
          const int row = cf * 16 + l15;
          const int eo = row * 256 + (((kc * 4 + l4) ^ (row & 7)) << 3);
          bf16x8 kbh = *(const bf16x8*)&SKh[cur][eo];
          bf16x8 kbl = *(const bf16x8*)&SKl[cur][eo];
          shh[cf] = mfma16(qfh[kc], kbh, shh[cf]);
          shl[cf] = mfma16(qfh[kc], kbl, shl[cf]);
          slh[cf] = mfma16(qfl[kc], kbh, slh[cf]);
        }
      }
      __builtin_amdgcn_s_setprio(0);
      // ---- online softmax (wave-local) ----
      float rr[4];
#pragma unroll
      for (int jj = 0; jj < 4; jj++) {
        const int prow = 16 * w + l4 * 4 + jj;
        const int qrow = q0 + prow;
        float s0v = shh[0][jj] + shl[0][jj] + slh[0][jj];
        float s1v = shh[1][jj] + shl[1][jj] + slh[1][jj];
        if (k0 + l15 > qrow) s0v = -1e30f;
        if (k0 + 16 + l15 > qrow) s1v = -1e30f;
        float mx = fmaxf(s0v, s1v);
#pragma unroll
        for (int off = 1; off < 16; off <<= 1) mx = fmaxf(mx, __shfl_xor(mx, off, 64));
        const float mnew = fmaxf(m_run[jj], mx);
        const float r = __expf(m_run[jj] - mnew);
        const float p0 = __expf(s0v - mnew);
        const float p1 = __expf(s1v - mnew);
        float rs = p0 + p1;
#pragma unroll
        for (int off = 1; off < 16; off <<= 1) rs += __shfl_xor(rs, off, 64);
        l_run[jj] = l_run[jj] * r + rs;
        m_run[jj] = mnew;
        rr[jj] = r;
        sP[prow * 40 + l15] = f2bf(p0);
        sP[prow * 40 + 16 + l15] = f2bf(p1);
      }
      // ---- rescale + PV (wave-local P: ds_write -> ds_read, same wave, no barrier) ----
#pragma unroll
      for (int ef = 0; ef < 16; ef++)
#pragma unroll
        for (int jj = 0; jj < 4; jj++) acc[ef][jj] *= rr[jj];
      bf16x8 pa = *(const bf16x8*)&sP[(16 * w + l15) * 40 + l4 * 8];
      __builtin_amdgcn_s_setprio(1);
#pragma unroll
      for (int ef = 0; ef < 16; ef++) {
        const int row = ef * 16 + l15;
        bf16x8 vb = *(const bf16x8*)&SV[cur][row * 32 + ((l4 ^ (row & 3)) << 3)];
        acc[ef] = mfma16(pa, vb, acc[ef]);
      }
      __builtin_amdgcn_s_setprio(0);
      __syncthreads();  // buffers free + staged DMA drained
    }
    // ---- finalize ----
    float li[4];
#pragma unroll
    for (int jj = 0; jj < 4; jj++) li[jj] = 1.0f / l_run[jj];
#pragma unroll
    for (int ef = 0; ef < 16; ef++)
#pragma unroll
      for (int jj = 0; jj < 4; jj++) {
        const int qrow = q0 + 16 * w + l4 * 4 + jj;
        const int mrow = qrow * 2 + b;
        const int col = h * 256 + ef * 16 + l15;
        Y[(size_t)mrow * 4096 + col] = f2bf(acc[ef][jj] * li[jj]);
      }
  }
}

// ---------------- proj GEMM (round-2/3 proven form) ----------------
__launch_bounds__(256, 2)
__global__ void k_proj(const u16* __restrict__ Yb, const u16* __restrict__ Wph,
                       float* __restrict__ Out) {
  const int n0 = blockIdx.x * 128;
  const int m0 = blockIdx.y * 128;
  __shared__ u16 sA[128 * 64];
  __shared__ u16 sB[128 * 64];
  const int tid = threadIdx.x;
  const int lane = tid & 63, w = tid >> 6;
  const int wr = w >> 1, wc = w & 1;
  const int l15 = lane & 15, l4 = lane >> 4;
  const f32x4 zero4 = {0.f, 0.f, 0.f, 0.f};
  f32x4 acc[4][4];
#pragma unroll
  for (int i = 0; i < 4; i++)
#pragma unroll
    for (int j = 0; j < 4; j++) acc[i][j] = zero4;

  for (int k0 = 0; k0 < 4096; k0 += 64) {
#pragma unroll
    for (int ii = 0; ii < 4; ++ii) {
      const int inst = w * 4 + ii;
      const int o = inst * 1024 + lane * 16;
      const int mr = o >> 7, c = (o & 127) >> 4;
      const int cs = c ^ (mr & 7);
      gload_lds16(Yb + (size_t)(m0 + mr) * 4096 + k0 + cs * 8, (char*)sA + inst * 1024);
      gload_lds16(Wph + (size_t)(n0 + mr) * 4096 + k0 + cs * 8, (char*)sB + inst * 1024);
    }
    __syncthreads();
#pragma unroll
    for (int kc = 0; kc < 2; ++kc) {
      bf16x8 af[4], bff[4];
#pragma unroll
      for (int i = 0; i < 4; i++) {
        const int mr = wr * 64 + i * 16 + l15;
        const int ch = (kc * 4 + l4) ^ (mr & 7);
        af[i] = *(const bf16x8*)&sA[mr * 64 + ch * 8];
      }
#pragma unroll
      for (int j = 0; j < 4; j++) {
        const int nr = wc * 64 + j * 16 + l15;
        const int ch = (kc * 4 + l4) ^ (nr & 7);
        bff[j] = *(const bf16x8*)&sB[nr * 64 + ch * 8];
      }
#pragma unroll
      for (int i = 0; i < 4; i++)
#pragma unroll
        for (int j = 0; j < 4; j++) acc[i][j] = mfma16(af[i], bff[j], acc[i][j]);
    }
    __syncthreads();
  }
#pragma unroll
  for (int i = 0; i < 4; i++)
#pragma unroll
    for (int j = 0; j < 4; j++)
#pragma unroll
      for (int jj = 0; jj < 4; jj++) {
        const int mrow = m0 + wr * 64 + i * 16 + l4 * 4 + jj;
        const int ncol = n0 + wc * 64 + j * 16 + l15;
        Out[(size_t)mrow * 2048 + ncol] = acc[i][j][jj];
      }
}

// ---------------- launcher ----------------
extern "C" void kernel_launch(void* const* d_in, const int* in_sizes, int n_in,
                              void* d_out, int out_size, void* d_ws, size_t ws_size,
                              hipStream_t stream) {
  (void)in_sizes; (void)n_in; (void)out_size; (void)ws_size;
  const float* X = (const float*)d_in[0];
  const float* Wq = (const float*)d_in[2];
  const float* Wp = (const float*)d_in[3];
  float* Out = (float*)d_out;
  char* ws = (char*)d_ws;
  const size_t MB = 1ull << 20;
  u16* Xh = (u16*)(ws + 0 * 32 * MB);
  u16* Xl = (u16*)(ws + 1 * 32 * MB);
  u16* Qh = (u16*)(ws + 2 * 32 * MB);
  u16* Ql = (u16*)(ws + 3 * 32 * MB);
  u16* Kh = (u16*)(ws + 4 * 32 * MB);
  u16* Kl = (u16*)(ws + 5 * 32 * MB);
  u16* Vv = (u16*)(ws + 6 * 32 * MB);
  u16* Wh = (u16*)(ws + 224 * MB);  // 96 MB
  u16* Wl = (u16*)(ws + 320 * MB);  // 96 MB
  u16* Vt = Wh;                     // alias: Wh dead after k_qkv2
  u16* Y = Wl;                      // alias: Wl dead after k_qkv2
  u16* Wph = Kh;                    // alias: Kh dead after k_attn
  u16* Wpl = Kl;                    // alias: Kl dead after k_attn

  k_convert<<<8192, 256, 0, stream>>>(X, Xh, Xl);
  k_convert<<<24576, 256, 0, stream>>>(Wq, Wh, Wl);
  k_qkv2<<<768, 512, 0, stream>>>(Xh, Xl, Wh, Wl, Qh, Ql, Kh, Kl, Vv);
  k_transpose<<<4096, 256, 0, stream>>>(Vv, Vt);
  k_attn<<<512, 256, 0, stream>>>(Qh, Ql, Kh, Kl, Vt, Y);
  k_convert<<<4096, 256, 0, stream>>>(Wp, Wph, Wpl);
  k_proj<<<dim3(16, 32), 256, 0, stream>>>(Y, Wph, Out);
}

// Round 10
// 1345.850 us; speedup vs baseline: 1.7931x; 1.1218x over previous
//
#include <hip/hip_runtime.h>
#include <stdint.h>

typedef unsigned short u16;
typedef __attribute__((ext_vector_type(4))) float f32x4;
typedef __attribute__((ext_vector_type(8))) __bf16 bf16x8;

typedef __attribute__((address_space(1))) void as1_void;
typedef __attribute__((address_space(3))) void as3_void;

#define SCALE_Q 11.313708498984761f

static_assert(sizeof(bf16x8) == 16, "bf16x8 must be 16B");

__device__ __forceinline__ u16 f2bf(float x) {
  union { float f; unsigned u; } v; v.f = x;
  return (u16)((v.u + 0x7FFFu + ((v.u >> 16) & 1u)) >> 16);
}
__device__ __forceinline__ float bf2f(u16 h) {
  union { unsigned u; float f; } v; v.u = ((unsigned)h) << 16;
  return v.f;
}
__device__ __forceinline__ f32x4 mfma16(bf16x8 a, bf16x8 b, f32x4 c) {
  return __builtin_amdgcn_mfma_f32_16x16x32_bf16(a, b, c, 0, 0, 0);
}
__device__ __forceinline__ void gload_lds16(const void* g, void* lds) {
  __builtin_amdgcn_global_load_lds((as1_void*)g, (as3_void*)lds, 16, 0, 0);
}

// ---------------- convert: fp32 -> bf16 hi/lo ----------------
__global__ void k_convert(const float* __restrict__ X, u16* __restrict__ Xh,
                          u16* __restrict__ Xl) {
  long idx = ((long)blockIdx.x * 256 + threadIdx.x) * 8;
  float4 a = *(const float4*)(X + idx);
  float4 b = *(const float4*)(X + idx + 4);
  float xs[8] = {a.x, a.y, a.z, a.w, b.x, b.y, b.z, b.w};
  union { u16 s[8]; uint4 v; } hu, lu;
#pragma unroll
  for (int i = 0; i < 8; ++i) {
    u16 h = f2bf(xs[i]);
    hu.s[i] = h;
    lu.s[i] = f2bf(xs[i] - bf2f(h));
  }
  *(uint4*)(Xh + idx) = hu.v;
  *(uint4*)(Xl + idx) = lu.v;
}

// ================ QKV GEMM (round-3 proven form, supply-roofline): 256x256, 8 waves ====
__launch_bounds__(512, 2)
__global__ void k_qkv2(const u16* __restrict__ Xh, const u16* __restrict__ Xl,
                       const u16* __restrict__ Wh, const u16* __restrict__ Wl,
                       u16* __restrict__ Qh, u16* __restrict__ Ql,
                       u16* __restrict__ Kh, u16* __restrict__ Kl,
                       u16* __restrict__ Vv) {
  const int bid = blockIdx.x;
  const int swz = (bid & 7) * 96 + (bid >> 3);  // 768 % 8 == 0 -> bijective
  const int nt = swz % 48, mt = swz / 48;
  const int n0 = nt * 256, m0 = mt * 256;
  const int seg = (n0 % 768) / 256;  // 0=q 1=k 2=v
  const bool qk = (seg < 2);
  const int hblk = n0 / 768;

  __shared__ u16 S[2][2][256 * 64];  // [buf][A/B][tile] = 128 KiB

  const int tid = threadIdx.x;
  const int lane = tid & 63, w = tid >> 6;
  const int wm = w >> 2, wn = w & 3;
  const int l15 = lane & 15, l4 = lane >> 4;

  const bool stB = (w >= 4);
  const int r_in = lane >> 3;
  const int c_in = lane & 7;
  const u16* g_hi = stB ? Wh : Xh;
  const u16* g_lo = stB ? Wl : Xl;
  const int gr0 = (stB ? n0 : m0);

  const int sh = (l4 ^ (l15 & 7)) * 8;
  const int sl = ((l4 ^ 4) ^ (l15 & 7)) * 8;

  const f32x4 zero4 = {0.f, 0.f, 0.f, 0.f};
  f32x4 acc[8][4];
#pragma unroll
  for (int i = 0; i < 8; i++)
#pragma unroll
    for (int j = 0; j < 4; j++) acc[i][j] = zero4;

  if (qk) {
    auto stage = [&](int buf, int k0) {
#pragma unroll
      for (int q8 = 0; q8 < 8; ++q8) {
        const int qi = (w & 3) * 8 + q8;
        const int row = qi * 8 + r_in;
        const int cs = c_in ^ (row & 7);
        const u16* src = (cs < 4) ? g_hi : g_lo;
        const int col = k0 + (cs & 3) * 8;
        gload_lds16(src + (size_t)(gr0 + row) * 4096 + col, &S[buf][stB ? 1 : 0][qi * 512]);
      }
    };
    stage(0, 0);
    __syncthreads();
    for (int t = 0; t < 128; ++t) {
      const int cur = t & 1;
      if (t + 1 < 128) stage(cur ^ 1, (t + 1) * 32);
      const u16* sAc = &S[cur][0][0];
      const u16* sBc = &S[cur][1][0];
      bf16x8 ah[8], al[8];
#pragma unroll
      for (int i = 0; i < 8; i++) {
        const int rb = (wm * 128 + i * 16 + l15) * 64;
        ah[i] = *(const bf16x8*)&sAc[rb + sh];
        al[i] = *(const bf16x8*)&sAc[rb + sl];
      }
      __builtin_amdgcn_s_setprio(1);
#pragma unroll
      for (int j = 0; j < 4; j++) {
        const int rb = (wn * 64 + j * 16 + l15) * 64;
        bf16x8 bh = *(const bf16x8*)&sBc[rb + sh];
        bf16x8 bl = *(const bf16x8*)&sBc[rb + sl];
#pragma unroll
        for (int i = 0; i < 8; i++) {
          acc[i][j] = mfma16(ah[i], bh, acc[i][j]);
          acc[i][j] = mfma16(ah[i], bl, acc[i][j]);
          acc[i][j] = mfma16(al[i], bh, acc[i][j]);
        }
      }
      __builtin_amdgcn_s_setprio(0);
      __syncthreads();
    }
  } else {
    auto stage = [&](int buf, int k0) {
#pragma unroll
      for (int q8 = 0; q8 < 8; ++q8) {
        const int qi = (w & 3) * 8 + q8;
        const int row = qi * 8 + r_in;
        const int cs = c_in ^ (row & 7);
        gload_lds16(g_hi + (size_t)(gr0 + row) * 4096 + k0 + cs * 8, &S[buf][stB ? 1 : 0][qi * 512]);
      }
    };
    stage(0, 0);
    __syncthreads();
    for (int t = 0; t < 64; ++t) {
      const int cur = t & 1;
      if (t + 1 < 64) stage(cur ^ 1, (t + 1) * 64);
      const u16* sAc = &S[cur][0][0];
      const u16* sBc = &S[cur][1][0];
      __builtin_amdgcn_s_setprio(1);
#pragma unroll
      for (int kc = 0; kc < 2; kc++) {
        const int so = ((kc * 4 + l4) ^ (l15 & 7)) * 8;
        bf16x8 av[8];
#pragma unroll
        for (int i = 0; i < 8; i++)
          av[i] = *(const bf16x8*)&sAc[(wm * 128 + i * 16 + l15) * 64 + so];
#pragma unroll
        for (int j = 0; j < 4; j++) {
          bf16x8 bv = *(const bf16x8*)&sBc[(wn * 64 + j * 16 + l15) * 64 + so];
#pragma unroll
          for (int i = 0; i < 8; i++) acc[i][j] = mfma16(av[i], bv, acc[i][j]);
        }
      }
      __builtin_amdgcn_s_setprio(0);
      __syncthreads();
    }
  }

#pragma unroll
  for (int i = 0; i < 8; i++)
#pragma unroll
    for (int j = 0; j < 4; j++)
#pragma unroll
      for (int jj = 0; jj < 4; jj++) {
        const int mrow = m0 + wm * 128 + i * 16 + l4 * 4 + jj;
        const int ecol = wn * 64 + j * 16 + l15;
        const int srow = mrow >> 1, b = mrow & 1;
        const size_t o = ((size_t)(b * 16 + hblk) * 2048 + srow) * 256 + ecol;
        float v = acc[i][j][jj];
        if (seg == 0) {
          v *= SCALE_Q;
          u16 hb = f2bf(v);
          Qh[o] = hb;
          Ql[o] = f2bf(v - bf2f(hb));
        } else if (seg == 1) {
          u16 hb = f2bf(v);
          Kh[o] = hb;
          Kl[o] = f2bf(v - bf2f(hb));
        } else {
          Vv[o] = f2bf(v);
        }
      }
}

// ---------------- V [bh][s][e] -> Vt [bh][e][s] ----------------
__global__ void k_transpose(const u16* __restrict__ Vv, u16* __restrict__ Vt) {
  const int bidx = blockIdx.x;
  const int et = bidx & 3;
  const int st = (bidx >> 2) & 31;
  const int bh = bidx >> 7;
  const int s0 = st * 64, e0 = et * 64;
  __shared__ u16 T[64][72];
  const int t = threadIdx.x;
  const int r = t >> 2, c = t & 3;
  const u16* src = Vv + (size_t)bh * 524288 + (size_t)(s0 + r) * 256 + e0 + c * 16;
  uint4 a = *(const uint4*)src;
  uint4 b = *(const uint4*)(src + 8);
  *(uint4*)&T[r][c * 16] = a;
  *(uint4*)&T[r][c * 16 + 8] = b;
  __syncthreads();
  union { u16 s[16]; uint4 v[2]; } pk;
#pragma unroll
  for (int i = 0; i < 16; i++) pk.s[i] = T[c * 16 + i][r];
  u16* dst = Vt + (size_t)bh * 524288 + (size_t)(e0 + r) * 2048 + s0 + c * 16;
  *(uint4*)dst = pk.v[0];
  *(uint4*)(dst + 8) = pk.v[1];
}

// ---------------- flash attention v3: QBLK=128, 8 waves, gload_lds dbuf ----------------
// Halves KV re-streaming vs QBLK=64 (supply 1.62 GB -> 0.84 GB).
// Wave w owns q-rows q0+16w..+15 for QK^T AND PV (P/r/l wave-local, 1 barrier/step).
// K LDS rows 256 elems (512B, 32 slots): slot^(row&7). V rows 32 elems (64B, 4 slots): slot^(row&3).
__launch_bounds__(512, 1)
__global__ void k_attn(const u16* __restrict__ Qh, const u16* __restrict__ Ql,
                       const u16* __restrict__ Kh, const u16* __restrict__ Kl,
                       const u16* __restrict__ Vt, u16* __restrict__ Y) {
  // bijective XCD swizzle: all 8 pair-blocks of one bh land on one XCD (K/V 3MB fits 4MB L2)
  const int bid = blockIdx.x;               // 256 blocks
  const int swz = (bid & 7) * 32 + (bid >> 3);
  const int bh = swz >> 3;
  const int pairIdx = swz & 7;              // 0..7
  const int b = bh >> 4, h = bh & 15;
  const int tid = threadIdx.x, lane = tid & 63, w = tid >> 6;  // 8 waves
  const int l15 = lane & 15, l4 = lane >> 4;

  __shared__ u16 SKh[2][32 * 256];  // 32 KiB
  __shared__ u16 SKl[2][32 * 256];  // 32 KiB
  __shared__ u16 SV[2][256 * 32];   // 32 KiB
  __shared__ u16 sP[128 * 40];      // wave-local P regions

  const u16* Qhb = Qh + (size_t)bh * 524288;
  const u16* Qlb = Ql + (size_t)bh * 524288;
  const u16* Khb = Kh + (size_t)bh * 524288;
  const u16* Klb = Kl + (size_t)bh * 524288;
  const u16* Vtb = Vt + (size_t)bh * 524288;

  const int kr_in = lane >> 5;   // K: row within 1KB inst (2 rows of 512B)
  const int ks_in = lane & 31;   // K: 16B slot within row
  const int vr_in = lane >> 2;   // V: row within 1KB inst (16 rows of 64B)
  const int vs_in = lane & 3;    // V: 16B slot within row

  const f32x4 zero4 = {0.f, 0.f, 0.f, 0.f};

  for (int rep = 0; rep < 2; ++rep) {
    const int tile = rep ? (15 - pairIdx) : pairIdx;  // paired for load balance
    const int q0 = tile * 128;
    // Q fragments (hi/lo) in registers: wave w owns rows q0+16w..+15
    bf16x8 qfh[8], qfl[8];
    {
      const int qrow = q0 + 16 * w + l15;
      const u16* ph = Qhb + (size_t)qrow * 256 + l4 * 8;
      const u16* pl = Qlb + (size_t)qrow * 256 + l4 * 8;
#pragma unroll
      for (int kc = 0; kc < 8; kc++) {
        qfh[kc] = *(const bf16x8*)(ph + kc * 32);
        qfl[kc] = *(const bf16x8*)(pl + kc * 32);
      }
    }
    f32x4 acc[16];
#pragma unroll
    for (int ef = 0; ef < 16; ef++) acc[ef] = zero4;
    float m_run[4], l_run[4];
#pragma unroll
    for (int jj = 0; jj < 4; jj++) { m_run[jj] = -1e30f; l_run[jj] = 0.f; }

    const int nsteps = 4 * tile + 4;

    auto stage = [&](int buf, int k0) {
#pragma unroll
      for (int q2 = 0; q2 < 2; ++q2) {
        const int qi = w * 2 + q2;  // 0..15
        {  // K hi+lo: inst covers keys qi*2, qi*2+1
          const int row = qi * 2 + kr_in;
          const int cs = ks_in ^ (row & 7);
          const size_t src = (size_t)(k0 + row) * 256 + cs * 8;
          gload_lds16(Khb + src, &SKh[buf][qi * 512]);
          gload_lds16(Klb + src, &SKl[buf][qi * 512]);
        }
        {  // V: inst covers e-rows qi*16..qi*16+15
          const int row = qi * 16 + vr_in;
          const int cs = vs_in ^ (row & 3);
          gload_lds16(Vtb + (size_t)row * 2048 + k0 + cs * 8, &SV[buf][qi * 512]);
        }
      }
    };

    stage(0, 0);
    __syncthreads();

    for (int st2 = 0; st2 < nsteps; ++st2) {
      const int k0 = st2 * 32;
      const int cur = st2 & 1;
      if (st2 + 1 < nsteps) stage(cur ^ 1, k0 + 32);
      // ---- QK^T 3-pass (wave's 16 q-rows x 32 keys) ----
      f32x4 shh[2], shl[2], slh[2];
#pragma unroll
      for (int cf = 0; cf < 2; cf++) { shh[cf] = zero4; shl[cf] = zero4; slh[cf] = zero4; }
      __builtin_amdgcn_s_setprio(1);
#pragma unroll
      for (int kc = 0; kc < 8; kc++) {
#pragma unroll
        for (int cf = 0; cf < 2; cf++) {
          const int row = cf * 16 + l15;
          const int eo = row * 256 + (((kc * 4 + l4) ^ (row & 7)) << 3);
          bf16x8 kbh = *(const bf16x8*)&SKh[cur][eo];
          bf16x8 kbl = *(const bf16x8*)&SKl[cur][eo];
          shh[cf] = mfma16(qfh[kc], kbh, shh[cf]);
          shl[cf] = mfma16(qfh[kc], kbl, shl[cf]);
          slh[cf] = mfma16(qfl[kc], kbh, slh[cf]);
        }
      }
      __builtin_amdgcn_s_setprio(0);
      // ---- online softmax (wave-local) ----
      float rr[4];
#pragma unroll
      for (int jj = 0; jj < 4; jj++) {
        const int prow = 16 * w + l4 * 4 + jj;
        const int qrow = q0 + prow;
        float s0v = shh[0][jj] + shl[0][jj] + slh[0][jj];
        float s1v = shh[1][jj] + shl[1][jj] + slh[1][jj];
        if (k0 + l15 > qrow) s0v = -1e30f;
        if (k0 + 16 + l15 > qrow) s1v = -1e30f;
        float mx = fmaxf(s0v, s1v);
#pragma unroll
        for (int off = 1; off < 16; off <<= 1) mx = fmaxf(mx, __shfl_xor(mx, off, 64));
        const float mnew = fmaxf(m_run[jj], mx);
        const float r = __expf(m_run[jj] - mnew);
        const float p0 = __expf(s0v - mnew);
        const float p1 = __expf(s1v - mnew);
        float rs = p0 + p1;
#pragma unroll
        for (int off = 1; off < 16; off <<= 1) rs += __shfl_xor(rs, off, 64);
        l_run[jj] = l_run[jj] * r + rs;
        m_run[jj] = mnew;
        rr[jj] = r;
        sP[prow * 40 + l15] = f2bf(p0);
        sP[prow * 40 + 16 + l15] = f2bf(p1);
      }
      // ---- rescale + PV (wave-local P: same-wave ds_write->ds_read, no barrier) ----
#pragma unroll
      for (int ef = 0; ef < 16; ef++)
#pragma unroll
        for (int jj = 0; jj < 4; jj++) acc[ef][jj] *= rr[jj];
      bf16x8 pa = *(const bf16x8*)&sP[(16 * w + l15) * 40 + l4 * 8];
      __builtin_amdgcn_s_setprio(1);
#pragma unroll
      for (int ef = 0; ef < 16; ef++) {
        const int row = ef * 16 + l15;
        bf16x8 vb = *(const bf16x8*)&SV[cur][row * 32 + ((l4 ^ (row & 3)) << 3)];
        acc[ef] = mfma16(pa, vb, acc[ef]);
      }
      __builtin_amdgcn_s_setprio(0);
      __syncthreads();  // buffers free + staged DMA drained
    }
    // ---- finalize ----
    float li[4];
#pragma unroll
    for (int jj = 0; jj < 4; jj++) li[jj] = 1.0f / l_run[jj];
#pragma unroll
    for (int ef = 0; ef < 16; ef++)
#pragma unroll
      for (int jj = 0; jj < 4; jj++) {
        const int qrow = q0 + 16 * w + l4 * 4 + jj;
        const int mrow = qrow * 2 + b;
        const int col = h * 256 + ef * 16 + l15;
        Y[(size_t)mrow * 4096 + col] = f2bf(acc[ef][jj] * li[jj]);
      }
    __syncthreads();
  }
}

// ---------------- proj GEMM v2: 256x128 tile, 8 waves, BK=64 dbuf stage-ahead ----------------
__launch_bounds__(512, 1)
__global__ void k_proj(const u16* __restrict__ Yb, const u16* __restrict__ Wph,
                       float* __restrict__ Out) {
  const int bid = blockIdx.x;                 // 256 blocks
  const int swz = (bid & 7) * 32 + (bid >> 3);  // bijective XCD swizzle
  const int nt = swz % 16, mt = swz / 16;
  const int n0 = nt * 128, m0 = mt * 256;

  __shared__ u16 SA[2][256 * 64];  // 64 KiB
  __shared__ u16 SB[2][128 * 64];  // 32 KiB

  const int tid = threadIdx.x;
  const int lane = tid & 63, w = tid >> 6;  // 8 waves
  const int wm = w >> 2, wn = w & 3;        // wave tile 128x32
  const int l15 = lane & 15, l4 = lane >> 4;

  const bool stB = (w >= 4);
  const int r_in = lane >> 3;
  const int c_in = lane & 7;

  const f32x4 zero4 = {0.f, 0.f, 0.f, 0.f};
  f32x4 acc[8][2];
#pragma unroll
  for (int i = 0; i < 8; i++)
#pragma unroll
    for (int j = 0; j < 2; j++) acc[i][j] = zero4;

  auto stage = [&](int buf, int k0) {
    if (!stB) {
      // waves 0-3: A tile, 32 insts (8 per wave)
#pragma unroll
      for (int q8 = 0; q8 < 8; ++q8) {
        const int qi = w * 8 + q8;
        const int row = qi * 8 + r_in;
        const int cs = c_in ^ (row & 7);
        gload_lds16(Yb + (size_t)(m0 + row) * 4096 + k0 + cs * 8, &SA[buf][qi * 512]);
      }
    } else {
      // waves 4-7: B tile, 16 insts (4 per wave)
#pragma unroll
      for (int q4 = 0; q4 < 4; ++q4) {
        const int qi = (w - 4) * 4 + q4;
        const int row = qi * 8 + r_in;
        const int cs = c_in ^ (row & 7);
        gload_lds16(Wph + (size_t)(n0 + row) * 4096 + k0 + cs * 8, &SB[buf][qi * 512]);
      }
    }
  };

  stage(0, 0);
  __syncthreads();
  for (int t = 0; t < 64; ++t) {
    const int cur = t & 1;
    if (t + 1 < 64) stage(cur ^ 1, (t + 1) * 64);
    __builtin_amdgcn_s_setprio(1);
#pragma unroll
    for (int kc = 0; kc < 2; kc++) {
      const int so = ((kc * 4 + l4) ^ (l15 & 7)) * 8;
      bf16x8 av[8];
#pragma unroll
      for (int i = 0; i < 8; i++)
        av[i] = *(const bf16x8*)&SA[cur][(wm * 128 + i * 16 + l15) * 64 + so];
#pragma unroll
      for (int j = 0; j < 2; j++) {
        bf16x8 bv = *(const bf16x8*)&SB[cur][(wn * 32 + j * 16 + l15) * 64 + so];
#pragma unroll
        for (int i = 0; i < 8; i++) acc[i][j] = mfma16(av[i], bv, acc[i][j]);
      }
    }
    __builtin_amdgcn_s_setprio(0);
    __syncthreads();
  }
#pragma unroll
  for (int i = 0; i < 8; i++)
#pragma unroll
    for (int j = 0; j < 2; j++)
#pragma unroll
      for (int jj = 0; jj < 4; jj++) {
        const int mrow = m0 + wm * 128 + i * 16 + l4 * 4 + jj;
        const int ncol = n0 + wn * 32 + j * 16 + l15;
        Out[(size_t)mrow * 2048 + ncol] = acc[i][j][jj];
      }
}

// ---------------- launcher ----------------
extern "C" void kernel_launch(void* const* d_in, const int* in_sizes, int n_in,
                              void* d_out, int out_size, void* d_ws, size_t ws_size,
                              hipStream_t stream) {
  (void)in_sizes; (void)n_in; (void)out_size; (void)ws_size;
  const float* X = (const float*)d_in[0];
  const float* Wq = (const float*)d_in[2];
  const float* Wp = (const float*)d_in[3];
  float* Out = (float*)d_out;
  char* ws = (char*)d_ws;
  const size_t MB = 1ull << 20;
  u16* Xh = (u16*)(ws + 0 * 32 * MB);
  u16* Xl = (u16*)(ws + 1 * 32 * MB);
  u16* Qh = (u16*)(ws + 2 * 32 * MB);
  u16* Ql = (u16*)(ws + 3 * 32 * MB);
  u16* Kh = (u16*)(ws + 4 * 32 * MB);
  u16* Kl = (u16*)(ws + 5 * 32 * MB);
  u16* Vv = (u16*)(ws + 6 * 32 * MB);
  u16* Wh = (u16*)(ws + 224 * MB);  // 96 MB
  u16* Wl = (u16*)(ws + 320 * MB);  // 96 MB
  u16* Vt = Wh;                     // alias: Wh dead after k_qkv2
  u16* Y = Wl;                      // alias: Wl dead after k_qkv2
  u16* Wph = Kh;                    // alias: Kh dead after k_attn
  u16* Wpl = Kl;                    // alias: Kl dead after k_attn

  k_convert<<<8192, 256, 0, stream>>>(X, Xh, Xl);
  k_convert<<<24576, 256, 0, stream>>>(Wq, Wh, Wl);
  k_qkv2<<<768, 512, 0, stream>>>(Xh, Xl, Wh, Wl, Qh, Ql, Kh, Kl, Vv);
  k_transpose<<<4096, 256, 0, stream>>>(Vv, Vt);
  k_attn<<<256, 512, 0, stream>>>(Qh, Ql, Kh, Kl, Vt, Y);
  k_convert<<<4096, 256, 0, stream>>>(Wp, Wph, Wpl);
  k_proj<<<256, 512, 0, stream>>>(Y, Wph, Out);
}